// Round 4
// baseline (841.710 us; speedup 1.0000x reference)
//
#include <hip/hip_runtime.h>
#include <math.h>

namespace {
constexpr int Cn = 256;
constexpr int Kn = 19;
constexpr int HW = 256 * 256;          // 65536
constexpr int P  = 4 * HW;             // 262144 pixels
constexpr float TAUv = 0.07f;
constexpr float EPSv = 1e-12f;

// workspace layout (floats)
constexpr int K0X4_OFF = 0;            // [4 wave-copies][19][256]
constexpr int K0N_OFF  = 4 * Kn * 256; // 19456: [19][256] normalized prototypes
constexpr int SUMS_OFF = K0N_OFF + Kn * 256;  // 24320: {loss_sum, num_pos}
constexpr int ZERO_N   = SUMS_OFF + 2;
constexpr int P1_GRID  = 1024;
constexpr int P3_GRID  = P / 512;      // 512 (2 px/thread)
constexpr int TROW     = 260;          // padded tile row stride (floats)
}

__global__ __launch_bounds__(256) void gc_init(float* __restrict__ ws) {
  int i = blockIdx.x * 256 + threadIdx.x;
  if (i < ZERO_N) ws[i] = 0.0f;
}

// Phase 1: k0[k][c] = sum over pixels of pos[k,p] * fnorm[c,p]
// Tile 32px x 256c in LDS (padded stride 260 -> b128-friendly).
// Consumer: lane L owns channels 4L..4L+3 (acc[19][4]); wave w owns pixels
// 8w..8w+7. Each wls broadcast float4 now feeds 4x more FMAs than 1 ch/lane.
__global__ __launch_bounds__(256) void gc_phase1(const float* __restrict__ feat,
                                                 const float* __restrict__ gt,
                                                 float* __restrict__ k0x4) {
  __shared__ float tile[32 * TROW];  // 33.3 KB
  __shared__ float part[256];        // per-(pixel,group) sumsq partials
  __shared__ float wls[32][20];      // [p][k] weights (pos ? rnorm : 0), padded

  const int t = threadIdx.x;
  const int p = t & 31;              // staging pixel
  const int g = t >> 5;              // staging channel group (8 x 32c)
  const int L = t & 63;              // consumer lane -> channels 4L..4L+3
  const int w = t >> 6;              // consumer wave -> pixels 8w..8w+7

  float acc[Kn * 4];
#pragma unroll
  for (int i = 0; i < Kn * 4; i++) acc[i] = 0.0f;

  for (int tid = blockIdx.x; tid < P / 32; tid += gridDim.x) {
    const int p0  = tid << 5;
    const int b   = p0 >> 16;              // HW == 65536
    const int hw0 = p0 & (HW - 1);
    const float* fb = feat + (size_t)b * (Cn * HW) + hw0 + p;

    __syncthreads();   // previous tile fully consumed

    // stage pixel p, channels g*32..g*32+31, two 16-deep batches
    float ss = 0.0f;
#pragma unroll
    for (int h = 0; h < 2; h++) {
      float v[16];
#pragma unroll
      for (int j = 0; j < 16; j++) v[j] = fb[(size_t)((g << 5) + (h << 4) + j) * HW];
#pragma unroll
      for (int j = 0; j < 16; j++) ss = fmaf(v[j], v[j], ss);
#pragma unroll
      for (int q = 0; q < 4; q++)
        *(float4*)&tile[p * TROW + (g << 5) + (h << 4) + (q << 2)] =
            make_float4(v[q * 4], v[q * 4 + 1], v[q * 4 + 2], v[q * 4 + 3]);
    }
    part[t] = ss;

    unsigned msk = 0;
    if (t < 32) {   // t == p; gt fetched once per pixel
      const float* gb = gt + (size_t)b * (Kn * HW) + hw0 + p;
#pragma unroll
      for (int k = 0; k < Kn; k++)
        msk |= (gb[(size_t)k * HW] == 1.0f) ? (1u << k) : 0u;
    }

    __syncthreads();   // tile + partials visible

    if (t < 32) {
      float fss = 0.0f;
#pragma unroll
      for (int q = 0; q < 8; q++) fss += part[(q << 5) + p];
      const float rn = 1.0f / fmaxf(sqrtf(fss), EPSv);
#pragma unroll
      for (int k = 0; k < Kn; k++) wls[p][k] = ((msk >> k) & 1u) ? rn : 0.0f;
      wls[p][19] = 0.0f;
    }

    __syncthreads();   // wls visible

    // consume: wave w handles pixels 8w..8w+7; lane L channels 4L..4L+3
#pragma unroll
    for (int i = 0; i < 8; i++) {
      const int pp = (w << 3) + i;
      const float4 f  = *(const float4*)&tile[pp * TROW + (L << 2)];  // conflict-free
      const float4 w0 = *(const float4*)&wls[pp][0];    // broadcast
      const float4 w1 = *(const float4*)&wls[pp][4];
      const float4 w2 = *(const float4*)&wls[pp][8];
      const float4 w3 = *(const float4*)&wls[pp][12];
      const float4 w4 = *(const float4*)&wls[pp][16];   // .w pad
      const float wk[19] = {w0.x,w0.y,w0.z,w0.w, w1.x,w1.y,w1.z,w1.w,
                            w2.x,w2.y,w2.z,w2.w, w3.x,w3.y,w3.z,w3.w,
                            w4.x,w4.y,w4.z};
#pragma unroll
      for (int k = 0; k < Kn; k++) {
        acc[k * 4 + 0] = fmaf(f.x, wk[k], acc[k * 4 + 0]);
        acc[k * 4 + 1] = fmaf(f.y, wk[k], acc[k * 4 + 1]);
        acc[k * 4 + 2] = fmaf(f.z, wk[k], acc[k * 4 + 2]);
        acc[k * 4 + 3] = fmaf(f.w, wk[k], acc[k * 4 + 3]);
      }
    }
  }

  // per-wave k0 copy quarters atomic contention
  float* k0w = k0x4 + (size_t)w * (Kn * 256);
#pragma unroll
  for (int k = 0; k < Kn; k++) {
#pragma unroll
    for (int j = 0; j < 4; j++)
      atomicAdd(&k0w[k * 256 + (L << 2) + j], acc[k * 4 + j]);
  }
}

// Phase 2: sum the 4 copies, row-normalize -> k0n
__global__ __launch_bounds__(256) void gc_phase2(const float* __restrict__ k0x4,
                                                 float* __restrict__ k0n) {
  __shared__ float ks[Kn * 256];
  const int t = threadIdx.x;
#pragma unroll
  for (int k = 0; k < Kn; k++) {
    float s = 0.0f;
#pragma unroll
    for (int w = 0; w < 4; w++) s += k0x4[w * (Kn * 256) + k * 256 + t];
    ks[k * 256 + t] = s;
  }
  __syncthreads();
  const int lane = t & 63;
  const int wv   = t >> 6;
  for (int r = wv; r < Kn; r += 4) {
    float s = 0.0f;
#pragma unroll
    for (int j = 0; j < 4; j++) {
      const float v = ks[r * 256 + (j << 6) + lane];
      s = fmaf(v, v, s);
    }
#pragma unroll
    for (int off = 32; off > 0; off >>= 1) s += __shfl_down(s, off);
    s = __shfl(s, 0);
    const float rn = 1.0f / fmaxf(sqrtf(s), EPSv);
#pragma unroll
    for (int j = 0; j < 4; j++) {
      const int c = (j << 6) + lane;
      k0n[r * 256 + c] = ks[r * 256 + c] * rn;
    }
  }
}

// Phase 3: logits + log-softmax + masked loss. 2 pixels/thread in registers,
// explicit next-chunk prefetch (no feat LDS round-trip); k0n in LDS once,
// float4 broadcasts feed 8 FMAs each. No launch_bounds occupancy cap.
__global__ __launch_bounds__(256) void gc_phase3(const float* __restrict__ feat,
                                                 const float* __restrict__ gt,
                                                 const float* __restrict__ k0n,
                                                 float* __restrict__ sums) {
  __shared__ float wco[Kn * 256];    // 19 KB coefficients

  const int t = threadIdx.x;
#pragma unroll
  for (int i = 0; i < Kn; i++) wco[i * 256 + t] = k0n[i * 256 + t];

  const int pix0 = blockIdx.x << 9;        // 512 px per block
  const int b    = pix0 >> 16;
  const int hw   = (pix0 & (HW - 1)) + t;  // px A = hw, px B = hw + 256
  const float* fb = feat + (size_t)b * (Cn * HW) + hw;

  float dot0[Kn], dot1[Kn];
#pragma unroll
  for (int k = 0; k < Kn; k++) { dot0[k] = 0.0f; dot1[k] = 0.0f; }
  float ss0 = 0.0f, ss1 = 0.0f;

  float ca[8], cb[8];
#pragma unroll
  for (int j = 0; j < 8; j++) {            // prefetch chunk 0 (16 loads in flight)
    ca[j] = fb[(size_t)j * HW];
    cb[j] = fb[(size_t)j * HW + 256];
  }
  __syncthreads();                         // wco ready

  for (int c0 = 0; c0 < Cn; c0 += 8) {
    float na[8], nb[8];
    if (c0 + 8 < Cn) {
#pragma unroll
      for (int j = 0; j < 8; j++) {        // prefetch next chunk
        na[j] = fb[(size_t)(c0 + 8 + j) * HW];
        nb[j] = fb[(size_t)(c0 + 8 + j) * HW + 256];
      }
    }
#pragma unroll
    for (int j = 0; j < 8; j++) {
      ss0 = fmaf(ca[j], ca[j], ss0);
      ss1 = fmaf(cb[j], cb[j], ss1);
    }
#pragma unroll
    for (int k = 0; k < Kn; k++) {
      const float4 w0 = *(const float4*)&wco[k * 256 + c0];      // broadcast
      const float4 w1 = *(const float4*)&wco[k * 256 + c0 + 4];
      float d0 = dot0[k], d1 = dot1[k];
      d0 = fmaf(ca[0], w0.x, d0); d0 = fmaf(ca[1], w0.y, d0);
      d0 = fmaf(ca[2], w0.z, d0); d0 = fmaf(ca[3], w0.w, d0);
      d0 = fmaf(ca[4], w1.x, d0); d0 = fmaf(ca[5], w1.y, d0);
      d0 = fmaf(ca[6], w1.z, d0); d0 = fmaf(ca[7], w1.w, d0);
      d1 = fmaf(cb[0], w0.x, d1); d1 = fmaf(cb[1], w0.y, d1);
      d1 = fmaf(cb[2], w0.z, d1); d1 = fmaf(cb[3], w0.w, d1);
      d1 = fmaf(cb[4], w1.x, d1); d1 = fmaf(cb[5], w1.y, d1);
      d1 = fmaf(cb[6], w1.z, d1); d1 = fmaf(cb[7], w1.w, d1);
      dot0[k] = d0; dot1[k] = d1;
    }
#pragma unroll
    for (int j = 0; j < 8; j++) { ca[j] = na[j]; cb[j] = nb[j]; }
  }

  const float sc0 = 1.0f / (fmaxf(sqrtf(ss0), EPSv) * TAUv);
  const float sc1 = 1.0f / (fmaxf(sqrtf(ss1), EPSv) * TAUv);
  float mx0 = -1e30f, mx1 = -1e30f;
#pragma unroll
  for (int k = 0; k < Kn; k++) {
    dot0[k] *= sc0; mx0 = fmaxf(mx0, dot0[k]);
    dot1[k] *= sc1; mx1 = fmaxf(mx1, dot1[k]);
  }
  float se0 = 0.0f, se1 = 0.0f;
#pragma unroll
  for (int k = 0; k < Kn; k++) {
    se0 += __expf(dot0[k] - mx0);
    se1 += __expf(dot1[k] - mx1);
  }
  const float lse0 = __logf(se0) + mx0;
  const float lse1 = __logf(se1) + mx1;

  const float* gb = gt + (size_t)b * (Kn * HW) + hw;
  float lsum = 0.0f, npos = 0.0f;
#pragma unroll
  for (int k = 0; k < Kn; k++) {
    if (gb[(size_t)k * HW] == 1.0f)       { lsum += lse0 - dot0[k]; npos += 1.0f; }
    if (gb[(size_t)k * HW + 256] == 1.0f) { lsum += lse1 - dot1[k]; npos += 1.0f; }
  }

#pragma unroll
  for (int off = 32; off > 0; off >>= 1) {
    lsum += __shfl_down(lsum, off);
    npos += __shfl_down(npos, off);
  }
  if ((t & 63) == 0) {
    atomicAdd(&sums[0], lsum);
    atomicAdd(&sums[1], npos);
  }
}

__global__ void gc_finalize(const float* __restrict__ sums, float* __restrict__ out) {
  if (threadIdx.x == 0 && blockIdx.x == 0)
    out[0] = sums[0] / sums[1];
}

extern "C" void kernel_launch(void* const* d_in, const int* in_sizes, int n_in,
                              void* d_out, int out_size, void* d_ws, size_t ws_size,
                              hipStream_t stream) {
  const float* feat = (const float*)d_in[0];
  const float* gt   = (const float*)d_in[1];
  float* ws  = (float*)d_ws;
  float* out = (float*)d_out;

  float* k0x4 = ws + K0X4_OFF;
  float* k0n  = ws + K0N_OFF;
  float* sums = ws + SUMS_OFF;

  gc_init<<<dim3((ZERO_N + 255) / 256), dim3(256), 0, stream>>>(ws);
  gc_phase1<<<dim3(P1_GRID), dim3(256), 0, stream>>>(feat, gt, k0x4);
  gc_phase2<<<dim3(1), dim3(256), 0, stream>>>(k0x4, k0n);
  gc_phase3<<<dim3(P3_GRID), dim3(256), 0, stream>>>(feat, gt, k0n, sums);
  gc_finalize<<<dim3(1), dim3(64), 0, stream>>>(sums, out);
}

// Round 5
// 615.675 us; speedup vs baseline: 1.3671x; 1.3671x over previous
//
#include <hip/hip_runtime.h>
#include <math.h>

namespace {
constexpr int Cn = 256;
constexpr int Kn = 19;
constexpr int HW = 256 * 256;          // 65536
constexpr int P  = 4 * HW;             // 262144 pixels
constexpr float TAUv = 0.07f;
constexpr float EPSv = 1e-12f;

constexpr int K0_OFF   = 0;                    // [19][256]
constexpr int K0N_OFF  = Kn * 256;             // 4864
constexpr int SUMS_OFF = K0N_OFF + Kn * 256;   // 9728
constexpr int ZERO_N   = SUMS_OFF + 2;
constexpr int P1_GRID  = 1024;
constexpr int P3_GRID  = P / 512;              // 512 (2 px/thread)
constexpr int TROW     = 260;                  // padded tile row stride (dwords)
}

__global__ __launch_bounds__(256) void gc_init(float* __restrict__ ws) {
  int i = blockIdx.x * 256 + threadIdx.x;
  if (i < ZERO_N) ws[i] = 0.0f;
}

// Phase 1: k0[k][c] += pos[k,p] * rnorm[p] * feat[c,p]
// Tile 32px x 256c in LDS. Consumer: wave-pair q (128 threads) handles
// pixels 16q..16q+15; thread tid2 owns channels {2*tid2, 2*tid2+1}
// (acc0[19]+acc1[19] = 38 VGPRs). Each wls float4 broadcast feeds 38 FMAs.
__global__ __launch_bounds__(256) void gc_phase1(const float* __restrict__ feat,
                                                 const float* __restrict__ gt,
                                                 float* __restrict__ k0) {
  __shared__ float tile[32 * TROW];  // 33.3 KB
  __shared__ float part[256];        // sumsq partials
  __shared__ float wls[32][20];      // [p][k] weights (pos ? rnorm : 0), padded

  const int t = threadIdx.x;
  const int p = t & 31;              // staging pixel
  const int g = t >> 5;              // staging channel group (8 x 32c)
  const int tid2 = t & 127;          // consumer: channels 2*tid2, 2*tid2+1
  const int pxo  = (t >> 7) << 4;    // consumer pixel offset: 0 or 16

  float acc0[Kn], acc1[Kn];
#pragma unroll
  for (int k = 0; k < Kn; k++) { acc0[k] = 0.0f; acc1[k] = 0.0f; }

  for (int tid = blockIdx.x; tid < P / 32; tid += gridDim.x) {
    const int p0  = tid << 5;
    const int b   = p0 >> 16;              // HW == 65536
    const int hw0 = p0 & (HW - 1);
    const float* fb = feat + (size_t)b * (Cn * HW) + hw0 + p;
    const float* gb = gt   + (size_t)b * (Kn * HW) + hw0;

    __syncthreads();   // previous tile fully consumed

    // stage pixel p, channels g*32..g*32+31, two 16-deep batches
    float ss = 0.0f;
#pragma unroll
    for (int h = 0; h < 2; h++) {
      float v[16];
#pragma unroll
      for (int j = 0; j < 16; j++) v[j] = fb[(size_t)((g << 5) + (h << 4) + j) * HW];
#pragma unroll
      for (int j = 0; j < 16; j++) ss = fmaf(v[j], v[j], ss);
#pragma unroll
      for (int q = 0; q < 4; q++)
        *(float4*)&tile[p * TROW + (g << 5) + (h << 4) + (q << 2)] =
            make_float4(v[q * 4], v[q * 4 + 1], v[q * 4 + 2], v[q * 4 + 3]);
    }
    part[t] = ss;

    // gt: 19k x 32px = 608 loads spread over 256 threads (<=3 each), 0/1 fill
#pragma unroll
    for (int r = 0; r < 3; r++) {
      const int i = t + (r << 8);
      if (i < Kn * 32) {
        const int kk = i >> 5, pp = i & 31;
        wls[pp][kk] = (gb[(size_t)kk * HW + pp] == 1.0f) ? 1.0f : 0.0f;
      }
    }

    __syncthreads();   // tile + part + wls01 visible

    if (t < 32) {      // t == p: fold rnorm into the weights
      float fss = 0.0f;
#pragma unroll
      for (int q = 0; q < 8; q++) fss += part[(q << 5) + p];
      const float rn = 1.0f / fmaxf(sqrtf(fss), EPSv);
#pragma unroll
      for (int k = 0; k < Kn; k++) wls[p][k] *= rn;
    }

    __syncthreads();   // wls scaled

    // consume: 16 pixels per wave-pair; b64 f-read + 5 b128 broadcasts -> 38 FMA
#pragma unroll 2
    for (int i = 0; i < 16; i++) {
      const int pp = pxo + i;
      const float2 f  = *(const float2*)&tile[pp * TROW + (tid2 << 1)];
      const float4 w0 = *(const float4*)&wls[pp][0];
      const float4 w1 = *(const float4*)&wls[pp][4];
      const float4 w2 = *(const float4*)&wls[pp][8];
      const float4 w3 = *(const float4*)&wls[pp][12];
      const float4 w4 = *(const float4*)&wls[pp][16];   // .w pad, unused
      const float fx = f.x, fy = f.y;
#define GC_STEP(idx, wv) \
      acc0[idx] = fmaf(fx, wv, acc0[idx]); acc1[idx] = fmaf(fy, wv, acc1[idx]);
      GC_STEP(0,  w0.x) GC_STEP(1,  w0.y) GC_STEP(2,  w0.z) GC_STEP(3,  w0.w)
      GC_STEP(4,  w1.x) GC_STEP(5,  w1.y) GC_STEP(6,  w1.z) GC_STEP(7,  w1.w)
      GC_STEP(8,  w2.x) GC_STEP(9,  w2.y) GC_STEP(10, w2.z) GC_STEP(11, w2.w)
      GC_STEP(12, w3.x) GC_STEP(13, w3.y) GC_STEP(14, w3.z) GC_STEP(15, w3.w)
      GC_STEP(16, w4.x) GC_STEP(17, w4.y) GC_STEP(18, w4.z)
#undef GC_STEP
    }
  }

  const int c0 = tid2 << 1;
#pragma unroll
  for (int k = 0; k < Kn; k++) {
    atomicAdd(&k0[k * 256 + c0],     acc0[k]);
    atomicAdd(&k0[k * 256 + c0 + 1], acc1[k]);
  }
}

// Phase 2: row-normalize k0 -> k0n
__global__ __launch_bounds__(256) void gc_phase2(const float* __restrict__ k0,
                                                 float* __restrict__ k0n) {
  const int lane = threadIdx.x & 63;
  const int wv   = threadIdx.x >> 6;
  for (int r = wv; r < Kn; r += 4) {
    float s = 0.0f;
#pragma unroll
    for (int j = 0; j < 4; j++) {
      const float v = k0[r * 256 + (j << 6) + lane];
      s = fmaf(v, v, s);
    }
#pragma unroll
    for (int off = 32; off > 0; off >>= 1) s += __shfl_down(s, off);
    s = __shfl(s, 0);
    const float rn = 1.0f / fmaxf(sqrtf(s), EPSv);
#pragma unroll
    for (int j = 0; j < 4; j++) {
      const int c = (j << 6) + lane;
      k0n[r * 256 + c] = k0[r * 256 + c] * rn;
    }
  }
}

// Phase 3: logits + log-softmax + masked loss. 2 px/thread, register
// prefetch; coefficients read from GLOBAL (uniform address -> L1/SMEM,
// keeps the LDS unit idle). No LDS at all.
__global__ __launch_bounds__(256) void gc_phase3(const float* __restrict__ feat,
                                                 const float* __restrict__ gt,
                                                 const float* __restrict__ k0n,
                                                 float* __restrict__ sums) {
  const int t = threadIdx.x;
  const int pix0 = blockIdx.x << 9;        // 512 px per block
  const int b    = pix0 >> 16;
  const int hw   = (pix0 & (HW - 1)) + t;  // px A = hw, px B = hw + 256
  const float* fb = feat + (size_t)b * (Cn * HW) + hw;

  float dot0[Kn], dot1[Kn];
#pragma unroll
  for (int k = 0; k < Kn; k++) { dot0[k] = 0.0f; dot1[k] = 0.0f; }
  float ss0 = 0.0f, ss1 = 0.0f;

  float ca[8], cb[8];
#pragma unroll
  for (int j = 0; j < 8; j++) {            // prefetch chunk 0
    ca[j] = fb[(size_t)j * HW];
    cb[j] = fb[(size_t)j * HW + 256];
  }

  for (int c0 = 0; c0 < Cn; c0 += 8) {
    float na[8], nb[8];
    if (c0 + 8 < Cn) {
#pragma unroll
      for (int j = 0; j < 8; j++) {        // prefetch next chunk
        na[j] = fb[(size_t)(c0 + 8 + j) * HW];
        nb[j] = fb[(size_t)(c0 + 8 + j) * HW + 256];
      }
    }
#pragma unroll
    for (int j = 0; j < 8; j++) {
      ss0 = fmaf(ca[j], ca[j], ss0);
      ss1 = fmaf(cb[j], cb[j], ss1);
    }
#pragma unroll
    for (int k = 0; k < Kn; k++) {
      const float4 w0 = *(const float4*)(k0n + k * 256 + c0);      // uniform
      const float4 w1 = *(const float4*)(k0n + k * 256 + c0 + 4);
      float d0 = dot0[k], d1 = dot1[k];
      d0 = fmaf(ca[0], w0.x, d0); d0 = fmaf(ca[1], w0.y, d0);
      d0 = fmaf(ca[2], w0.z, d0); d0 = fmaf(ca[3], w0.w, d0);
      d0 = fmaf(ca[4], w1.x, d0); d0 = fmaf(ca[5], w1.y, d0);
      d0 = fmaf(ca[6], w1.z, d0); d0 = fmaf(ca[7], w1.w, d0);
      d1 = fmaf(cb[0], w0.x, d1); d1 = fmaf(cb[1], w0.y, d1);
      d1 = fmaf(cb[2], w0.z, d1); d1 = fmaf(cb[3], w0.w, d1);
      d1 = fmaf(cb[4], w1.x, d1); d1 = fmaf(cb[5], w1.y, d1);
      d1 = fmaf(cb[6], w1.z, d1); d1 = fmaf(cb[7], w1.w, d1);
      dot0[k] = d0; dot1[k] = d1;
    }
#pragma unroll
    for (int j = 0; j < 8; j++) { ca[j] = na[j]; cb[j] = nb[j]; }
  }

  const float sc0 = 1.0f / (fmaxf(sqrtf(ss0), EPSv) * TAUv);
  const float sc1 = 1.0f / (fmaxf(sqrtf(ss1), EPSv) * TAUv);
  float mx0 = -1e30f, mx1 = -1e30f;
#pragma unroll
  for (int k = 0; k < Kn; k++) {
    dot0[k] *= sc0; mx0 = fmaxf(mx0, dot0[k]);
    dot1[k] *= sc1; mx1 = fmaxf(mx1, dot1[k]);
  }
  float se0 = 0.0f, se1 = 0.0f;
#pragma unroll
  for (int k = 0; k < Kn; k++) {
    se0 += __expf(dot0[k] - mx0);
    se1 += __expf(dot1[k] - mx1);
  }
  const float lse0 = __logf(se0) + mx0;
  const float lse1 = __logf(se1) + mx1;

  const float* gb = gt + (size_t)b * (Kn * HW) + hw;
  float lsum = 0.0f, npos = 0.0f;
#pragma unroll
  for (int k = 0; k < Kn; k++) {
    if (gb[(size_t)k * HW] == 1.0f)       { lsum += lse0 - dot0[k]; npos += 1.0f; }
    if (gb[(size_t)k * HW + 256] == 1.0f) { lsum += lse1 - dot1[k]; npos += 1.0f; }
  }

#pragma unroll
  for (int off = 32; off > 0; off >>= 1) {
    lsum += __shfl_down(lsum, off);
    npos += __shfl_down(npos, off);
  }
  if ((t & 63) == 0) {
    atomicAdd(&sums[0], lsum);
    atomicAdd(&sums[1], npos);
  }
}

__global__ void gc_finalize(const float* __restrict__ sums, float* __restrict__ out) {
  if (threadIdx.x == 0 && blockIdx.x == 0)
    out[0] = sums[0] / sums[1];
}

extern "C" void kernel_launch(void* const* d_in, const int* in_sizes, int n_in,
                              void* d_out, int out_size, void* d_ws, size_t ws_size,
                              hipStream_t stream) {
  const float* feat = (const float*)d_in[0];
  const float* gt   = (const float*)d_in[1];
  float* ws  = (float*)d_ws;
  float* out = (float*)d_out;

  float* k0   = ws + K0_OFF;
  float* k0n  = ws + K0N_OFF;
  float* sums = ws + SUMS_OFF;

  gc_init<<<dim3((ZERO_N + 255) / 256), dim3(256), 0, stream>>>(ws);
  gc_phase1<<<dim3(P1_GRID), dim3(256), 0, stream>>>(feat, gt, k0);
  gc_phase2<<<dim3(1), dim3(256), 0, stream>>>(k0, k0n);
  gc_phase3<<<dim3(P3_GRID), dim3(256), 0, stream>>>(feat, gt, k0n, sums);
  gc_finalize<<<dim3(1), dim3(64), 0, stream>>>(sums, out);
}